// Round 3
// baseline (206.289 us; speedup 1.0000x reference)
//
#include <hip/hip_runtime.h>

typedef float v4f __attribute__((ext_vector_type(4)));
typedef float v2f __attribute__((ext_vector_type(2)));

#define LOG2E  1.4426950408889634f
#define NLOG2E (-1.4426950408889634f)
#define C2L2E  2.8853900817779268f   // 2*log2(e)
#define LN2    0.6931471805599453f

__device__ __forceinline__ float fexp2(float x){ return __builtin_amdgcn_exp2f(x); }
__device__ __forceinline__ float flog2(float x){ return __builtin_amdgcn_logf(x); }
__device__ __forceinline__ float frcp (float x){ return __builtin_amdgcn_rcpf(x); }
__device__ __forceinline__ float hsum(v4f v){ return (v.x+v.y)+(v.z+v.w); }

// ---------------------------------------------------------------------------
// prep: bid 0..127  : A/B = (x @ W1half (+b1)) * 2log2e   (X[2048x128] @ W[128x256])
//       bid 128..191: xpT = (x @ Wp)^T                    (X[2048x128] @ Wp[128x128])
//       bid 192..199: sq[row] = ||x_row||^2
// ---------------------------------------------------------------------------
__global__ __launch_bounds__(256) void prep_kernel(
    const float* __restrict__ x, const float* __restrict__ W1,
    const float* __restrict__ b1, const float* __restrict__ Wp,
    float* __restrict__ sq, float* __restrict__ Abuf,
    float* __restrict__ Bbuf, float* __restrict__ xpT)
{
  const int bid = blockIdx.x, t = threadIdx.x;
  if (bid >= 192) {                       // ---- sq ----
    int row = (bid - 192) * 256 + t;      // 0..2047
    const v4f* xv = (const v4f*)(x + row * 128);
    float s = 0.f;
#pragma unroll
    for (int q = 0; q < 32; q++) { v4f v = xv[q]; s += hsum(v * v); }
    sq[row] = s;
    return;
  }
  __shared__ v4f Xs[64 * 9];              // 64 rows x 8 f4, pad 9, slot-swizzled
  __shared__ v4f Ws[32 * 16];             // 32 dd  x 16 f4 (64 cols)
  const bool isAB = bid < 128;
  int it, ct;
  if (isAB) { it = bid >> 2; ct = bid & 3; }
  else      { int q = bid - 128; it = q >> 1; ct = q & 1; }
  const int row0 = it * 64;
  const int tx = t & 15, ty = t >> 4;
  const int r0 = ty * 4, c0 = tx * 4;
  v4f acc[4] = {};                        // acc[i] over 4 cols

  for (int dd0 = 0; dd0 < 128; dd0 += 32) {
    __syncthreads();
#pragma unroll
    for (int s2 = 0; s2 < 2; s2++) {      // stage X (coalesced), swizzled slot
      int idx = t + s2 * 256;
      int row = idx >> 3, k4 = idx & 7;
      v4f v = *(const v4f*)(x + (row0 + row) * 128 + dd0 + k4 * 4);
      Xs[row * 9 + ((k4 + (row >> 2)) & 7)] = v;
    }
#pragma unroll
    for (int s2 = 0; s2 < 2; s2++) {      // stage W (f4 along cols)
      int idx = t + s2 * 256;
      int dd = idx >> 4, cf4 = idx & 15;
      v4f v;
      if (isAB) {
        int cl = cf4 * 4; int half = cl >> 5; int k = cl & 31;
        v = *(const v4f*)(W1 + (ct * 256 + half * 128 + dd0 + dd) * 32 + k);
      } else {
        v = *(const v4f*)(Wp + (dd0 + dd) * 128 + ct * 64 + cf4 * 4);
      }
      Ws[dd * 16 + cf4] = v;
    }
    __syncthreads();
#pragma unroll
    for (int dd4 = 0; dd4 < 8; dd4++) {
      int sa = (dd4 + ty) & 7;
      v4f a0 = Xs[(r0 + 0) * 9 + sa], a1 = Xs[(r0 + 1) * 9 + sa];
      v4f a2 = Xs[(r0 + 2) * 9 + sa], a3 = Xs[(r0 + 3) * 9 + sa];
#pragma unroll
      for (int u = 0; u < 4; u++) {
        v4f bv = Ws[(dd4 * 4 + u) * 16 + tx];
        acc[0] += a0[u] * bv; acc[1] += a1[u] * bv;
        acc[2] += a2[u] * bv; acc[3] += a3[u] * bv;
      }
    }
  }

  if (isAB) {
    const int h = ct; const int half = c0 >> 5; const int k = c0 & 31;
    v4f bias = {};
    if (half == 0) bias = *(const v4f*)(b1 + h * 32 + k);
    float* dst = (half == 0) ? Abuf : Bbuf;
#pragma unroll
    for (int i = 0; i < 4; i++) {
      int rg = row0 + r0 + i; int b = rg >> 9; int ir = rg & 511;
      v4f o = (acc[i] + bias) * C2L2E;
      *(v4f*)(dst + ((b * 4 + h) * 512 + ir) * 32 + k) = o;
    }
  } else {
    int rg0 = row0 + r0; int b = rg0 >> 9; int ir0 = rg0 & 511;
#pragma unroll
    for (int u = 0; u < 4; u++) {
      int c = ct * 64 + c0 + u;
      v4f o = { acc[0][u], acc[1][u], acc[2][u], acc[3][u] };
      *(v4f*)(xpT + (b * 128 + c) * 512 + ir0) = o;
    }
  }
}

// ---------------------------------------------------------------------------
// adj (fused dist2 + dgf): 16x32 tile, 1x2 micro, 8 blocks/CU.
//   gram staged 2x32k chunks/round; heads staged 2/round. 8 barriers total.
//   LDS layout [sec][row][slot], slot=(k4+g)&7 chosen so A-reads broadcast and
//   B-reads cover all 32 banks exactly 2x (conflict-free for b128).
// ---------------------------------------------------------------------------
__global__ __launch_bounds__(256, 8) void adj_kernel(
    const float* __restrict__ x, const float* __restrict__ sq,
    const float* __restrict__ Abuf, const float* __restrict__ Bbuf,
    const float* __restrict__ W2, const float* __restrict__ b2g,
    float* __restrict__ ADJ)
{
  const int jt = blockIdx.x, it = blockIdx.y, b = blockIdx.z;  // it: 0..31
  const int t = threadIdx.x, tx = t & 15, ty = t >> 4;
  __shared__ v4f As[2 * 16 * 9];   // [sec][row 0..15][slot]
  __shared__ v4f Bs[2 * 32 * 9];   // [sec][col 0..31][slot]
  __shared__ v4f W2s[32];
  __shared__ float hb[4];

  if (t < 32) W2s[t] = ((const v4f*)W2)[t];
  if (t < 4) {
    float s = b2g[t];
    for (int k = 0; k < 32; k++) s += W2[t * 32 + k];
    hb[t] = s;
  }

  const int row0g = it * 16, col0g = jt * 32;
  // staging decomposition (A: 1 v4f/thread, B: 2 v4f/thread)
  const int a_sec = t >> 7, a_row = (t >> 3) & 15, a_k4 = t & 7;
  const int a_slot = (a_k4 + a_row) & 7;
  const float* xb = x + (size_t)b * 512 * 128;

  // ---- phase 1: gram (K=128 in 2 rounds of 2x32 chunks) ----
  v4f gacc0 = {}, gacc1 = {};
#pragma unroll
  for (int half = 0; half < 2; half++) {
    if (half) __syncthreads();
    As[a_sec * 144 + a_row * 9 + a_slot] =
      *(const v4f*)(xb + (row0g + a_row) * 128 + half * 64 + a_sec * 32 + a_k4 * 4);
#pragma unroll
    for (int s = 0; s < 2; s++) {
      int idx = t + s * 256;
      int sec = idx >> 8, col = (idx >> 3) & 31, k4 = idx & 7;
      Bs[sec * 288 + col * 9 + ((k4 + (col >> 1)) & 7)] =
        *(const v4f*)(xb + (col0g + col) * 128 + half * 64 + sec * 32 + k4 * 4);
    }
    __syncthreads();
#pragma unroll
    for (int c = 0; c < 2; c++) {
#pragma unroll
      for (int k4 = 0; k4 < 8; k4++) {
        int sa = (k4 + ty) & 7, sb = (k4 + tx) & 7;
        v4f a0 = As[c * 144 + ty * 9 + sa];
        v4f b0 = Bs[c * 288 + (2 * tx) * 9 + sb];
        v4f b1 = Bs[c * 288 + (2 * tx + 1) * 9 + sb];
        gacc0 += a0 * b0; gacc1 += a0 * b1;
      }
    }
  }
  float si  = sq[b * 512 + row0g + ty];
  float sj0 = sq[b * 512 + col0g + 2 * tx];
  float sj1 = sq[b * 512 + col0g + 2 * tx + 1];
  float d2L0 = fmaxf(si + sj0 - 2.f * hsum(gacc0), 0.f) * NLOG2E;
  float d2L1 = fmaxf(si + sj1 - 2.f * hsum(gacc1), 0.f) * NLOG2E;

  // ---- phase 2: heads, 2 per staging round ----
  float acc0 = 0.f, acc1 = 0.f;
#pragma unroll
  for (int g = 0; g < 2; g++) {
    __syncthreads();
    As[a_sec * 144 + a_row * 9 + a_slot] =
      *(const v4f*)(Abuf + ((size_t)((b * 4 + g * 2 + a_sec) * 512 + row0g + a_row)) * 32 + a_k4 * 4);
#pragma unroll
    for (int s = 0; s < 2; s++) {
      int idx = t + s * 256;
      int sec = idx >> 8, col = (idx >> 3) & 31, k4 = idx & 7;
      Bs[sec * 288 + col * 9 + ((k4 + (col >> 1)) & 7)] =
        *(const v4f*)(Bbuf + ((size_t)((b * 4 + g * 2 + sec) * 512 + col0g + col)) * 32 + k4 * 4);
    }
    __syncthreads();
#pragma unroll
    for (int hh = 0; hh < 2; hh++) {
      int h = g * 2 + hh;
      float hbv = hb[h];
      float s0 = hbv, s1 = hbv;
#pragma unroll
      for (int k4 = 0; k4 < 8; k4++) {
        int sa = (k4 + ty) & 7, sb = (k4 + tx) & 7;
        v4f a0 = As[hh * 144 + ty * 9 + sa];
        v4f b0 = Bs[hh * 288 + (2 * tx) * 9 + sb];
        v4f b1 = Bs[hh * 288 + (2 * tx + 1) * 9 + sb];
        v4f w2v = W2s[h * 8 + k4];
#pragma unroll
        for (int u = 0; u < 4; u++) {
          float wm = -2.f * w2v[u];
          float au = a0[u];
          float e0 = fexp2(au + b0[u]);
          s0 = fmaf(wm, frcp(e0 + 1.f), s0);
          float e1 = fexp2(au + b1[u]);
          s1 = fmaf(wm, frcp(e1 + 1.f), s1);
        }
      }
      float u20 = fexp2(s0 * LOG2E);               // e^s
      float sg0 = LN2 * flog2(1.f + u20);          // softplus
      float den0 = fmaf(2.f * sg0, sg0, 1e-6f);
      acc0 += fexp2(d2L0 * frcp(den0));
      float u21 = fexp2(s1 * LOG2E);
      float sg1 = LN2 * flog2(1.f + u21);
      float den1 = fmaf(2.f * sg1, sg1, 1e-6f);
      acc1 += fexp2(d2L1 * frcp(den1));
    }
  }
  v2f o = { acc0 * 0.25f, acc1 * 0.25f };
  *(v2f*)(ADJ + ((size_t)(b * 512 + row0g + ty)) * 512 + col0g + 2 * tx) = o;
}

// ---------------------------------------------------------------------------
// out_gemm: part[ks] = ADJ[:, kslice] @ xpT[:, kslice]^T   (K=512 split by 2)
// ---------------------------------------------------------------------------
__global__ __launch_bounds__(256) void out_gemm(
    const float* __restrict__ ADJ, const float* __restrict__ xpT,
    float* __restrict__ part)
{
  const int ct = blockIdx.x;            // 0..3 : 32-col tile
  const int it = blockIdx.y;            // 0..15: 32-row tile
  const int z = blockIdx.z; const int b = z >> 1, ks = z & 1;
  const int t = threadIdx.x, tx = t & 15, ty = t >> 4;
  const int r0 = 2 * ty, c0 = 2 * tx;
  __shared__ v4f Ajs[32 * 9], Xps[32 * 9];
  v4f acc[4] = {};
  const int row = t >> 3, k4l = t & 7, slot = (k4l + (row >> 1)) & 7;

  for (int k0 = ks * 256; k0 < ks * 256 + 256; k0 += 32) {
    __syncthreads();
    Ajs[row * 9 + slot] = *(const v4f*)(ADJ + ((size_t)(b * 512 + it * 32 + row)) * 512 + k0 + k4l * 4);
    Xps[row * 9 + slot] = *(const v4f*)(xpT + ((size_t)(b * 128 + ct * 32 + row)) * 512 + k0 + k4l * 4);
    __syncthreads();
#pragma unroll
    for (int k4 = 0; k4 < 8; k4++) {
      int sa = (k4 + ty) & 7, sb = (k4 + tx) & 7;
      v4f a0 = Ajs[(r0 + 0) * 9 + sa], a1 = Ajs[(r0 + 1) * 9 + sa];
      v4f b0 = Xps[(c0 + 0) * 9 + sb], b1v = Xps[(c0 + 1) * 9 + sb];
      acc[0] += a0 * b0; acc[1] += a0 * b1v;
      acc[2] += a1 * b0; acc[3] += a1 * b1v;
    }
  }
  float* dst = part + ((size_t)((ks * 4 + b) * 512 + it * 32 + r0)) * 128 + ct * 32 + c0;
  v2f o0 = { hsum(acc[0]), hsum(acc[1]) };
  v2f o1 = { hsum(acc[2]), hsum(acc[3]) };
  *(v2f*)dst = o0;
  *(v2f*)(dst + 128) = o1;
}

__global__ __launch_bounds__(256) void reduce_out(
    const float* __restrict__ part, const float* __restrict__ bp,
    float* __restrict__ out)
{
  int g = blockIdx.x * 256 + threadIdx.x;   // v4f index, 65536 total
  const v4f* p = (const v4f*)part;
  v4f s = p[g] + p[g + 65536];
  v4f bv = ((const v4f*)bp)[g & 31];
  ((v4f*)out)[g] = s + bv;
}

// ---------------------------------------------------------------------------
extern "C" void kernel_launch(void* const* d_in, const int* in_sizes, int n_in,
                              void* d_out, int out_size, void* d_ws, size_t ws_size,
                              hipStream_t stream) {
  const float* x  = (const float*)d_in[0];
  const float* W1 = (const float*)d_in[1];
  const float* b1 = (const float*)d_in[2];
  const float* W2 = (const float*)d_in[3];
  const float* b2 = (const float*)d_in[4];
  const float* Wp = (const float*)d_in[5];
  const float* bp = (const float*)d_in[6];
  float* out = (float*)d_out;

  float* ws  = (float*)d_ws;
  float* sq  = ws;                 // 2048
  float* A   = ws + 2048;          // 262144
  float* Bb  = A + 262144;         // 262144
  float* xpT = Bb + 262144;        // 262144
  float* ADJ = xpT + 262144;       // 1048576
  float* part = ADJ + 1048576;     // 524288

  prep_kernel<<<200, 256, 0, stream>>>(x, W1, b1, Wp, sq, A, Bb, xpT);
  adj_kernel<<<dim3(16, 32, 4), 256, 0, stream>>>(x, sq, A, Bb, W2, b2, ADJ);
  out_gemm<<<dim3(4, 16, 8), 256, 0, stream>>>(ADJ, xpT, part);
  reduce_out<<<256, 256, 0, stream>>>(part, bp, out);
}